// Round 1
// baseline (20191.794 us; speedup 1.0000x reference)
//
#include <hip/hip_runtime.h>
#include <hip/hip_bf16.h>
#include <math.h>

#define L 12
#define H 16
#define E 1024
#define V 8192
#define T 512
#define B 4
#define D 64
#define M_ROWS (B*T)   // 2048
#define FF (4*E)       // 4096

// ---------------------------------------------------------------- embedding
__global__ void embed_kernel(const int* __restrict__ x, const float* __restrict__ tok,
                             const float* __restrict__ pos, float* __restrict__ h) {
  int idx = blockIdx.x * blockDim.x + threadIdx.x;   // over M_ROWS*E/4 float4s
  int row = idx >> 8;                                // E/4 = 256 float4 per row
  int c   = idx & 255;
  int t   = row & (T - 1);
  int tokid = x[row];
  const float4* t4 = (const float4*)tok;
  const float4* p4 = (const float4*)pos;
  float4 a = t4[(size_t)tokid * 256 + c];
  float4 p = p4[(size_t)t * 256 + c];
  float4 r;
  r.x = a.x + p.x; r.y = a.y + p.y; r.z = a.z + p.z; r.w = a.w + p.w;
  ((float4*)h)[idx] = r;
}

// ---------------------------------------------------------------- layernorm
__global__ __launch_bounds__(256) void ln_kernel(const float* __restrict__ x,
    const float* __restrict__ w, const float* __restrict__ b, float* __restrict__ y) {
  const int row = blockIdx.x;
  const int tid = threadIdx.x;
  const float4* xr = (const float4*)(x + (size_t)row * E);
  float4 v = xr[tid];
  float s = v.x + v.y + v.z + v.w;
  float q = v.x*v.x + v.y*v.y + v.z*v.z + v.w*v.w;
  #pragma unroll
  for (int off = 32; off > 0; off >>= 1) {
    s += __shfl_down(s, off);
    q += __shfl_down(q, off);
  }
  __shared__ float ss[4], qq[4];
  int wave = tid >> 6;
  if ((tid & 63) == 0) { ss[wave] = s; qq[wave] = q; }
  __syncthreads();
  s = ss[0] + ss[1] + ss[2] + ss[3];
  q = qq[0] + qq[1] + qq[2] + qq[3];
  float mean = s * (1.0f / E);
  float var  = q * (1.0f / E) - mean * mean;
  float rstd = rsqrtf(var + 1e-5f);
  float4 wv = ((const float4*)w)[tid];
  float4 bv = ((const float4*)b)[tid];
  float4 o;
  o.x = (v.x - mean) * rstd * wv.x + bv.x;
  o.y = (v.y - mean) * rstd * wv.y + bv.y;
  o.z = (v.z - mean) * rstd * wv.z + bv.z;
  o.w = (v.w - mean) * rstd * wv.w + bv.w;
  ((float4*)(y + (size_t)row * E))[tid] = o;
}

// ---------------------------------------------------------------- fp32 GEMM
// C[M,N] = epi(A[M,K] @ W[K,N] + bias [, R])
// EPI: 0 = bias only, 1 = bias + exact GELU, 2 = bias + residual add (R)
#define BM 128
#define BN 128
#define BK 16
#define PAD 4

__device__ __forceinline__ float gelu_exact(float x) {
  return 0.5f * x * (1.0f + erff(x * 0.70710678118654752f));
}

template<int EPI>
__device__ __forceinline__ void gemm_body(const float* __restrict__ A,
    const float* __restrict__ W, const float* __restrict__ bias,
    const float* __restrict__ R, float* __restrict__ C,
    int N, int K, int m0, int n0,
    float (*As)[BM + PAD], float (*Bs)[BN + PAD]) {
  const int tid = threadIdx.x;
  const int tm = tid >> 4, tn = tid & 15;
  float acc[8][8] = {};
  for (int k0 = 0; k0 < K; k0 += BK) {
    #pragma unroll
    for (int i = 0; i < 2; ++i) {
      int f = tid + i * 256;
      int ar = f >> 2, ac = (f & 3) << 2;                 // A: 128 rows x 16 cols
      float4 av = *(const float4*)(A + (size_t)(m0 + ar) * K + (k0 + ac));
      As[ac + 0][ar] = av.x; As[ac + 1][ar] = av.y;
      As[ac + 2][ar] = av.z; As[ac + 3][ar] = av.w;
      int br = f >> 5, bc = (f & 31) << 2;                // B: 16 rows x 128 cols
      *(float4*)(&Bs[br][bc]) = *(const float4*)(W + (size_t)(k0 + br) * N + (n0 + bc));
    }
    __syncthreads();
    #pragma unroll
    for (int kk = 0; kk < BK; ++kk) {
      float4 A0 = *(const float4*)(&As[kk][tm * 4]);
      float4 A1 = *(const float4*)(&As[kk][64 + tm * 4]);
      float4 B0 = *(const float4*)(&Bs[kk][tn * 4]);
      float4 B1 = *(const float4*)(&Bs[kk][64 + tn * 4]);
      float a[8]  = {A0.x, A0.y, A0.z, A0.w, A1.x, A1.y, A1.z, A1.w};
      float bb[8] = {B0.x, B0.y, B0.z, B0.w, B1.x, B1.y, B1.z, B1.w};
      #pragma unroll
      for (int r = 0; r < 8; ++r)
        #pragma unroll
        for (int c = 0; c < 8; ++c)
          acc[r][c] = fmaf(a[r], bb[c], acc[r][c]);
    }
    __syncthreads();
  }
  #pragma unroll
  for (int r = 0; r < 8; ++r) {
    int row = m0 + (r >> 2) * 64 + tm * 4 + (r & 3);
    #pragma unroll
    for (int cg = 0; cg < 2; ++cg) {
      int col = n0 + cg * 64 + tn * 4;
      float4 res = make_float4(acc[r][cg*4+0], acc[r][cg*4+1], acc[r][cg*4+2], acc[r][cg*4+3]);
      if (bias) {
        float4 bv = *(const float4*)(bias + col);
        res.x += bv.x; res.y += bv.y; res.z += bv.z; res.w += bv.w;
      }
      if (EPI == 1) {
        res.x = gelu_exact(res.x); res.y = gelu_exact(res.y);
        res.z = gelu_exact(res.z); res.w = gelu_exact(res.w);
      }
      if (EPI == 2) {
        float4 rv = *(const float4*)(R + (size_t)row * N + col);
        res.x += rv.x; res.y += rv.y; res.z += rv.z; res.w += rv.w;
      }
      *(float4*)(C + (size_t)row * N + col) = res;
    }
  }
}

template<int EPI>
__global__ __launch_bounds__(256) void gemm_kernel(const float* __restrict__ A,
    const float* __restrict__ W, const float* __restrict__ bias,
    const float* __restrict__ R, float* __restrict__ C, int N, int K) {
  __shared__ float As[BK][BM + PAD];
  __shared__ float Bs[BK][BN + PAD];
  gemm_body<EPI>(A, W, bias, R, C, N, K, blockIdx.y * BM, blockIdx.x * BN, As, Bs);
}

struct QKVArgs {
  const float* W0; const float* W1; const float* W2;
  const float* b0; const float* b1; const float* b2;
  float* o0; float* o1; float* o2;
};

__global__ __launch_bounds__(256) void qkv_kernel(const float* __restrict__ A,
    QKVArgs a, int N, int K) {
  __shared__ float As[BK][BM + PAD];
  __shared__ float Bs[BK][BN + PAD];
  int z = blockIdx.z;
  const float* W    = (z == 0) ? a.W0 : (z == 1) ? a.W1 : a.W2;
  const float* bias = (z == 0) ? a.b0 : (z == 1) ? a.b1 : a.b2;
  float*       C    = (z == 0) ? a.o0 : (z == 1) ? a.o1 : a.o2;
  gemm_body<0>(A, W, bias, nullptr, C, N, K, blockIdx.y * BM, blockIdx.x * BN, As, Bs);
}

// ---------------------------------------------------------------- attention
// Faithful to reference: S[i,j] = dot(k_i, q_j) * E^-0.5, mask j<=i,
// softmax over j, out[i] = sum_j P[i,j] * v_j.  One thread per (b,h,i).
__global__ __launch_bounds__(256) void attn_kernel(const float* __restrict__ q,
    const float* __restrict__ k, const float* __restrict__ v, float* __restrict__ o) {
  const int b  = blockIdx.z;
  const int hh = blockIdx.y;
  const int i  = blockIdx.x * 256 + threadIdx.x;
  const float scale = 0.03125f;            // E^-0.5 = 1/32 (full n_embd, per source)
  const size_t rowOff = ((size_t)(b * T + i)) * E + hh * D;
  const float4* kp = (const float4*)(k + rowOff);
  float4 kk4[16];
  #pragma unroll
  for (int u = 0; u < 16; ++u) kk4[u] = kp[u];
  const float* qbase = q + (size_t)(b * T) * E + hh * D;
  const float* vbase = v + (size_t)(b * T) * E + hh * D;

  // pass 1: online max + denom
  float m = -INFINITY, lsum = 0.0f;
  for (int j = 0; j <= i; ++j) {
    const float4* qj = (const float4*)(qbase + (size_t)j * E);
    float4 sa = make_float4(0.f, 0.f, 0.f, 0.f);
    #pragma unroll
    for (int u = 0; u < 16; ++u) {
      float4 qv = qj[u];
      sa.x = fmaf(kk4[u].x, qv.x, sa.x);
      sa.y = fmaf(kk4[u].y, qv.y, sa.y);
      sa.z = fmaf(kk4[u].z, qv.z, sa.z);
      sa.w = fmaf(kk4[u].w, qv.w, sa.w);
    }
    float s = (sa.x + sa.y + sa.z + sa.w) * scale;
    if (s > m) { lsum = lsum * __expf(m - s) + 1.0f; m = s; }
    else       { lsum += __expf(s - m); }
  }
  float inv = 1.0f / lsum;

  // pass 2: recompute scores, accumulate P @ V
  float4 acc[16];
  #pragma unroll
  for (int u = 0; u < 16; ++u) acc[u] = make_float4(0.f, 0.f, 0.f, 0.f);
  for (int j = 0; j <= i; ++j) {
    const float4* qj = (const float4*)(qbase + (size_t)j * E);
    float4 sa = make_float4(0.f, 0.f, 0.f, 0.f);
    #pragma unroll
    for (int u = 0; u < 16; ++u) {
      float4 qv = qj[u];
      sa.x = fmaf(kk4[u].x, qv.x, sa.x);
      sa.y = fmaf(kk4[u].y, qv.y, sa.y);
      sa.z = fmaf(kk4[u].z, qv.z, sa.z);
      sa.w = fmaf(kk4[u].w, qv.w, sa.w);
    }
    float s = (sa.x + sa.y + sa.z + sa.w) * scale;
    float p = __expf(s - m) * inv;
    const float4* vj = (const float4*)(vbase + (size_t)j * E);
    #pragma unroll
    for (int u = 0; u < 16; ++u) {
      float4 vv = vj[u];
      acc[u].x = fmaf(p, vv.x, acc[u].x);
      acc[u].y = fmaf(p, vv.y, acc[u].y);
      acc[u].z = fmaf(p, vv.z, acc[u].z);
      acc[u].w = fmaf(p, vv.w, acc[u].w);
    }
  }
  float4* op = (float4*)(o + rowOff);
  #pragma unroll
  for (int u = 0; u < 16; ++u) op[u] = acc[u];
}

// ---------------------------------------------------------------- launch
extern "C" void kernel_launch(void* const* d_in, const int* in_sizes, int n_in,
                              void* d_out, int out_size, void* d_ws, size_t ws_size,
                              hipStream_t stream) {
  const int*   x       = (const int*)  d_in[0];
  const float* tok_emb = (const float*)d_in[1];
  const float* pos_emb = (const float*)d_in[2];
  const float* Wq   = (const float*)d_in[3];
  const float* bq   = (const float*)d_in[4];
  const float* Wk   = (const float*)d_in[5];
  const float* bk   = (const float*)d_in[6];
  const float* Wv   = (const float*)d_in[7];
  const float* bv   = (const float*)d_in[8];
  const float* Wo   = (const float*)d_in[9];
  const float* bo   = (const float*)d_in[10];
  const float* ln1w = (const float*)d_in[11];
  const float* ln1b = (const float*)d_in[12];
  const float* ln2w = (const float*)d_in[13];
  const float* ln2b = (const float*)d_in[14];
  const float* W1   = (const float*)d_in[15];
  const float* b1   = (const float*)d_in[16];
  const float* W2   = (const float*)d_in[17];
  const float* b2   = (const float*)d_in[18];
  const float* lnfw = (const float*)d_in[19];
  const float* lnfb = (const float*)d_in[20];
  const float* headW= (const float*)d_in[21];
  float* out = (float*)d_out;

  float* ws = (float*)d_ws;
  float* h   = ws;
  float* y   = h + (size_t)M_ROWS * E;
  float* q   = y + (size_t)M_ROWS * E;
  float* k   = q + (size_t)M_ROWS * E;
  float* v   = k + (size_t)M_ROWS * E;
  float* mlp = v + (size_t)M_ROWS * E;   // M_ROWS x FF

  embed_kernel<<<(M_ROWS * E / 4) / 256, 256, 0, stream>>>(x, tok_emb, pos_emb, h);

  for (int l = 0; l < L; ++l) {
    ln_kernel<<<M_ROWS, 256, 0, stream>>>(h, ln1w + l * E, ln1b + l * E, y);

    QKVArgs qa;
    qa.W0 = Wq + (size_t)l * E * E; qa.W1 = Wk + (size_t)l * E * E; qa.W2 = Wv + (size_t)l * E * E;
    qa.b0 = bq + l * E;             qa.b1 = bk + l * E;             qa.b2 = bv + l * E;
    qa.o0 = q;                      qa.o1 = k;                      qa.o2 = v;
    qkv_kernel<<<dim3(E / BN, M_ROWS / BM, 3), 256, 0, stream>>>(y, qa, E, E);

    attn_kernel<<<dim3(T / 256, H, B), 256, 0, stream>>>(q, k, v, y);

    gemm_kernel<2><<<dim3(E / BN, M_ROWS / BM), 256, 0, stream>>>(
        y, Wo + (size_t)l * E * E, bo + l * E, h, h, E, E);

    ln_kernel<<<M_ROWS, 256, 0, stream>>>(h, ln2w + l * E, ln2b + l * E, y);

    gemm_kernel<1><<<dim3(FF / BN, M_ROWS / BM), 256, 0, stream>>>(
        y, W1 + (size_t)l * E * FF, b1 + l * FF, nullptr, mlp, FF, E);

    gemm_kernel<2><<<dim3(E / BN, M_ROWS / BM), 256, 0, stream>>>(
        mlp, W2 + (size_t)l * FF * E, b2 + l * E, h, h, E, FF);
  }

  ln_kernel<<<M_ROWS, 256, 0, stream>>>(h, lnfw, lnfb, y);

  gemm_kernel<0><<<dim3(V / BN, M_ROWS / BM), 256, 0, stream>>>(
      y, headW, nullptr, nullptr, out, V, E);
}

// Round 9
// 6796.992 us; speedup vs baseline: 2.9707x; 2.9707x over previous
//
#include <hip/hip_runtime.h>
#include <hip/hip_bf16.h>
#include <math.h>

#define L 12
#define H 16
#define E 1024
#define V 8192
#define T 512
#define B 4
#define D 64
#define M_ROWS (B*T)   // 2048
#define FF (4*E)       // 4096

typedef __attribute__((ext_vector_type(8))) short    s16x8;
typedef __attribute__((ext_vector_type(8))) __bf16   bf16x8;
typedef __attribute__((ext_vector_type(4))) float    f32x4;

__device__ __forceinline__ unsigned short f2bf(float x) {
  __hip_bfloat16 h = __float2bfloat16(x);   // RNE
  return __builtin_bit_cast(unsigned short, h);
}
__device__ __forceinline__ float bf2f(unsigned short u) {
  return __bfloat162float(__builtin_bit_cast(__hip_bfloat16, u));
}

__device__ __forceinline__ f32x4 mfma16(s16x8 a, s16x8 b, f32x4 c) {
  return __builtin_amdgcn_mfma_f32_16x16x32_bf16(
      __builtin_bit_cast(bf16x8, a), __builtin_bit_cast(bf16x8, b), c, 0, 0, 0);
}

__device__ __forceinline__ float gelu_exact(float x) {
  return 0.5f * x * (1.0f + erff(x * 0.70710678118654752f));
}

// ---------------------------------------------------------------- embedding
__global__ void embed_kernel(const int* __restrict__ x, const float* __restrict__ tok,
                             const float* __restrict__ pos, float* __restrict__ h) {
  int idx = blockIdx.x * blockDim.x + threadIdx.x;
  int row = idx >> 8;                                // E/4 = 256 float4 per row
  int c   = idx & 255;
  int t   = row & (T - 1);
  int tokid = x[row];
  const float4* t4 = (const float4*)tok;
  const float4* p4 = (const float4*)pos;
  float4 a = t4[(size_t)tokid * 256 + c];
  float4 p = p4[(size_t)t * 256 + c];
  float4 r;
  r.x = a.x + p.x; r.y = a.y + p.y; r.z = a.z + p.z; r.w = a.w + p.w;
  ((float4*)h)[idx] = r;
}

// ---------------------------------------------------------------- layernorm -> hi/lo planes
__global__ __launch_bounds__(256) void ln_kernel(const float* __restrict__ x,
    const float* __restrict__ w, const float* __restrict__ b,
    unsigned short* __restrict__ yH, unsigned short* __restrict__ yL) {
  const int row = blockIdx.x;
  const int tid = threadIdx.x;
  const float4* xr = (const float4*)(x + (size_t)row * E);
  float4 v = xr[tid];
  float s = v.x + v.y + v.z + v.w;
  float q = v.x*v.x + v.y*v.y + v.z*v.z + v.w*v.w;
  #pragma unroll
  for (int off = 32; off > 0; off >>= 1) {
    s += __shfl_down(s, off);
    q += __shfl_down(q, off);
  }
  __shared__ float ss[4], qq[4];
  int wave = tid >> 6;
  if ((tid & 63) == 0) { ss[wave] = s; qq[wave] = q; }
  __syncthreads();
  s = ss[0] + ss[1] + ss[2] + ss[3];
  q = qq[0] + qq[1] + qq[2] + qq[3];
  float mean = s * (1.0f / E);
  float var  = q * (1.0f / E) - mean * mean;
  float rstd = rsqrtf(var + 1e-5f);
  float4 wv = ((const float4*)w)[tid];
  float4 bv = ((const float4*)b)[tid];
  float o0 = (v.x - mean) * rstd * wv.x + bv.x;
  float o1 = (v.y - mean) * rstd * wv.y + bv.y;
  float o2 = (v.z - mean) * rstd * wv.z + bv.z;
  float o3 = (v.w - mean) * rstd * wv.w + bv.w;
  ushort4 h4, l4;
  h4.x = f2bf(o0); l4.x = f2bf(o0 - bf2f(h4.x));
  h4.y = f2bf(o1); l4.y = f2bf(o1 - bf2f(h4.y));
  h4.z = f2bf(o2); l4.z = f2bf(o2 - bf2f(h4.z));
  h4.w = f2bf(o3); l4.w = f2bf(o3 - bf2f(h4.w));
  *(ushort4*)(yH + (size_t)row * E + tid * 4) = h4;
  *(ushort4*)(yL + (size_t)row * E + tid * 4) = l4;
}

// ---------------------------------------------------------------- weight transpose+split
// W [K][N] fp32 (row stride N) -> hi/lo bf16 [N'][K] where N' = grid.x*64
__device__ __forceinline__ void convert_body(const float* __restrict__ W,
    unsigned short* __restrict__ hi, unsigned short* __restrict__ lo,
    int K, int N, float (*tile)[65]) {
  const int k0 = blockIdx.y * 64, n0 = blockIdx.x * 64;
  const int t = threadIdx.x;
  const int r = t >> 4, c = (t & 15) * 4;
  #pragma unroll
  for (int i = 0; i < 4; ++i) {
    const float4 v = *(const float4*)(W + (size_t)(k0 + r + i * 16) * N + n0 + c);
    tile[r + i * 16][c + 0] = v.x;
    tile[r + i * 16][c + 1] = v.y;
    tile[r + i * 16][c + 2] = v.z;
    tile[r + i * 16][c + 3] = v.w;
  }
  __syncthreads();
  const int n = t >> 2, ks = (t & 3) * 16;
  unsigned short hb[16], lb[16];
  #pragma unroll
  for (int j = 0; j < 16; ++j) {
    float x = tile[ks + j][n];
    unsigned short hh = f2bf(x);
    hb[j] = hh;
    lb[j] = f2bf(x - bf2f(hh));
  }
  size_t o = (size_t)(n0 + n) * K + k0 + ks;
  #define PK2(a, b) (((unsigned int)(a)) | (((unsigned int)(b)) << 16))
  uint4 H0 = make_uint4(PK2(hb[0],hb[1]), PK2(hb[2],hb[3]), PK2(hb[4],hb[5]), PK2(hb[6],hb[7]));
  uint4 H1 = make_uint4(PK2(hb[8],hb[9]), PK2(hb[10],hb[11]), PK2(hb[12],hb[13]), PK2(hb[14],hb[15]));
  uint4 L0 = make_uint4(PK2(lb[0],lb[1]), PK2(lb[2],lb[3]), PK2(lb[4],lb[5]), PK2(lb[6],lb[7]));
  uint4 L1 = make_uint4(PK2(lb[8],lb[9]), PK2(lb[10],lb[11]), PK2(lb[12],lb[13]), PK2(lb[14],lb[15]));
  *(uint4*)(hi + o) = H0; *(uint4*)(hi + o + 8) = H1;
  *(uint4*)(lo + o) = L0; *(uint4*)(lo + o + 8) = L1;
  #undef PK2
}

__global__ __launch_bounds__(256) void convert_w(const float* __restrict__ W,
    unsigned short* __restrict__ hi, unsigned short* __restrict__ lo, int K, int N) {
  __shared__ float tile[64][65];
  convert_body(W, hi, lo, K, N, tile);
}

struct Cv4 { const float* src[4]; unsigned short* hi[4]; unsigned short* lo[4]; };
__global__ __launch_bounds__(256) void convert_qkvo(Cv4 p) {
  __shared__ float tile[64][65];
  int z = blockIdx.z;
  convert_body(p.src[z], p.hi[z], p.lo[z], E, E, tile);
}

// ---------------------------------------------------------------- split-bf16 MFMA GEMM
// C[M,N] = epi(A @ W + bias). A: hi/lo [M][K]; W: hi/lo [N][K] (pre-transposed).
// EPI 0: fp32 out (+bias). EPI 1: +bias, GELU -> hi/lo planes. EPI 2: h += acc+bias.
__device__ __forceinline__ int swz(int kg, int row) {
  return (kg ^ (row & 3) ^ ((row >> 2) & 3)) & 3;
}

template<int EPI>
__device__ __forceinline__ void gemm_mfma_body(
    const unsigned short* __restrict__ aH, const unsigned short* __restrict__ aL,
    const unsigned short* __restrict__ bHp, const unsigned short* __restrict__ bLp,
    const float* __restrict__ bias, float* __restrict__ hio, float* __restrict__ outF,
    unsigned short* __restrict__ outHi, unsigned short* __restrict__ outLo,
    int N, int K, int m0, int n0,
    unsigned short* AsH, unsigned short* AsL, unsigned short* BsH, unsigned short* BsL) {
  const int tid = threadIdx.x;
  const int lane = tid & 63, wave = tid >> 6;
  const int wm = (wave >> 1) * 64, wn = (wave & 1) * 64;
  const int lr = lane & 15, kg = lane >> 4;

  f32x4 acc[4][4];
  #pragma unroll
  for (int m = 0; m < 4; ++m)
    #pragma unroll
    for (int n = 0; n < 4; ++n) acc[m][n] = (f32x4){0.f, 0.f, 0.f, 0.f};

  for (int k0 = 0; k0 < K; k0 += 32) {
    #pragma unroll
    for (int i = 0; i < 2; ++i) {
      int g = tid + i * 256;           // granule id: 128 rows x 4 slots
      int row = g >> 2, slot = g & 3;
      int dst = row * 32 + swz(slot, row) * 8;
      size_t asrc = (size_t)(m0 + row) * K + k0 + slot * 8;
      size_t bsrc = (size_t)(n0 + row) * K + k0 + slot * 8;
      *(s16x8*)(AsH + dst) = *(const s16x8*)(aH + asrc);
      *(s16x8*)(AsL + dst) = *(const s16x8*)(aL + asrc);
      *(s16x8*)(BsH + dst) = *(const s16x8*)(bHp + bsrc);
      *(s16x8*)(BsL + dst) = *(const s16x8*)(bLp + bsrc);
    }
    __syncthreads();
    s16x8 ah[4], al[4], bh[4], bl[4];
    #pragma unroll
    for (int m = 0; m < 4; ++m) {
      int row = wm + m * 16 + lr;
      int off = row * 32 + swz(kg, row) * 8;
      ah[m] = *(const s16x8*)(AsH + off);
      al[m] = *(const s16x8*)(AsL + off);
    }
    #pragma unroll
    for (int n = 0; n < 4; ++n) {
      int row = wn + n * 16 + lr;
      int off = row * 32 + swz(kg, row) * 8;
      bh[n] = *(const s16x8*)(BsH + off);
      bl[n] = *(const s16x8*)(BsL + off);
    }
    #pragma unroll
    for (int m = 0; m < 4; ++m)
      #pragma unroll
      for (int n = 0; n < 4; ++n) {
        acc[m][n] = mfma16(al[m], bh[n], acc[m][n]);
        acc[m][n] = mfma16(ah[m], bl[n], acc[m][n]);
        acc[m][n] = mfma16(ah[m], bh[n], acc[m][n]);
      }
    __syncthreads();
  }

  #pragma unroll
  for (int m = 0; m < 4; ++m) {
    #pragma unroll
    for (int n = 0; n < 4; ++n) {
      int col = n0 + wn + n * 16 + lr;
      float bv = bias ? bias[col] : 0.0f;
      #pragma unroll
      for (int r = 0; r < 4; ++r) {
        int row = m0 + wm + m * 16 + kg * 4 + r;
        size_t o = (size_t)row * N + col;
        float val = acc[m][n][r] + bv;
        if (EPI == 0) outF[o] = val;
        if (EPI == 1) {
          float g = gelu_exact(val);
          unsigned short hh = f2bf(g);
          outHi[o] = hh;
          outLo[o] = f2bf(g - bf2f(hh));
        }
        if (EPI == 2) hio[o] = hio[o] + val;
      }
    }
  }
}

template<int EPI>
__global__ __launch_bounds__(256) void gemm_mfma(
    const unsigned short* aH, const unsigned short* aL,
    const unsigned short* bH, const unsigned short* bL, const float* bias,
    float* hio, float* outF, unsigned short* oHi, unsigned short* oLo, int N, int K) {
  __shared__ unsigned short AsH[4096], AsL[4096], BsH[4096], BsL[4096];
  gemm_mfma_body<EPI>(aH, aL, bH, bL, bias, hio, outF, oHi, oLo, N, K,
                      blockIdx.y * 128, blockIdx.x * 128, AsH, AsL, BsH, BsL);
}

struct QkvP {
  const unsigned short* wH[3]; const unsigned short* wL[3];
  const float* bias[3]; float* out[3];
};
__global__ __launch_bounds__(256) void qkv_gemm(const unsigned short* yH,
                                                const unsigned short* yL, QkvP p) {
  __shared__ unsigned short AsH[4096], AsL[4096], BsH[4096], BsL[4096];
  int z = blockIdx.z;
  gemm_mfma_body<0>(yH, yL, p.wH[z], p.wL[z], p.bias[z], nullptr, p.out[z],
                    nullptr, nullptr, E, E, blockIdx.y * 128, blockIdx.x * 128,
                    AsH, AsL, BsH, BsL);
}

// ---------------------------------------------------------------- attention
// Faithful: S[i,j] = dot(k_i, q_j) * E^-0.5, mask j<=i, softmax over j,
// out[i] = sum_j P[i,j] * v_j. Writes ctx as hi/lo bf16 planes.
#define TI 64
#define TJ 64

__global__ __launch_bounds__(256) void attn_kernel(const float* __restrict__ q,
    const float* __restrict__ k, const float* __restrict__ v,
    unsigned short* __restrict__ oH, unsigned short* __restrict__ oL) {
  __shared__ float Qs[TJ][D];
  __shared__ float Vs[TJ][D];
  const int b    = blockIdx.z;
  const int hh   = blockIdx.y;
  const int i0   = blockIdx.x * TI;
  const int tid  = threadIdx.x;
  const int lane = tid & 63;
  const int wave = tid >> 6;
  const int r    = lane >> 2;
  const int t    = lane & 3;
  const int i    = i0 + wave * 16 + r;
  const float scale = 0.03125f;        // E^-0.5 = 1/32 (full n_embd, per source)

  const size_t bhOff = (size_t)b * T * E + (size_t)hh * D;

  const float4* kp = (const float4*)(k + bhOff + (size_t)i * E + t * 16);
  float4 kk[4];
  #pragma unroll
  for (int u = 0; u < 4; ++u) kk[u] = kp[u];

  float4 acc[4];
  #pragma unroll
  for (int u = 0; u < 4; ++u) acc[u] = make_float4(0.f, 0.f, 0.f, 0.f);
  float m = -INFINITY, lsum = 0.0f;

  const int stager = tid >> 4;
  const int stagec = (tid & 15) * 4;

  for (int jt = 0; jt <= blockIdx.x; ++jt) {
    __syncthreads();
    #pragma unroll
    for (int p = 0; p < 4; ++p) {
      int jj = stager + p * 16;
      size_t g = bhOff + (size_t)(jt * TJ + jj) * E + stagec;
      *(float4*)(&Qs[jj][stagec]) = *(const float4*)(q + g);
      *(float4*)(&Vs[jj][stagec]) = *(const float4*)(v + g);
    }
    __syncthreads();

    int jmax = i - jt * TJ + 1;
    if (jmax > TJ) jmax = TJ;

    for (int jj = 0; jj < jmax; ++jj) {
      float s = 0.0f;
      #pragma unroll
      for (int u = 0; u < 4; ++u) {
        float4 qv = *(const float4*)(&Qs[jj][t * 16 + u * 4]);
        s = fmaf(kk[u].x, qv.x, s);
        s = fmaf(kk[u].y, qv.y, s);
        s = fmaf(kk[u].z, qv.z, s);
        s = fmaf(kk[u].w, qv.w, s);
      }
      s += __shfl_xor(s, 1);
      s += __shfl_xor(s, 2);
      s *= scale;
      float p;
      if (s > m) {
        float ex = __expf(m - s);
        lsum = lsum * ex + 1.0f;
        #pragma unroll
        for (int u = 0; u < 4; ++u) {
          acc[u].x *= ex; acc[u].y *= ex; acc[u].z *= ex; acc[u].w *= ex;
        }
        m = s; p = 1.0f;
      } else {
        p = __expf(s - m);
        lsum += p;
      }
      #pragma unroll
      for (int u = 0; u < 4; ++u) {
        float4 vv = *(const float4*)(&Vs[jj][t * 16 + u * 4]);
        acc[u].x = fmaf(p, vv.x, acc[u].x);
        acc[u].y = fmaf(p, vv.y, acc[u].y);
        acc[u].z = fmaf(p, vv.z, acc[u].z);
        acc[u].w = fmaf(p, vv.w, acc[u].w);
      }
    }
  }

  float inv = 1.0f / lsum;
  size_t ob = bhOff + (size_t)i * E + t * 16;
  #pragma unroll
  for (int u = 0; u < 4; ++u) {
    float a0 = acc[u].x * inv, a1 = acc[u].y * inv, a2 = acc[u].z * inv, a3 = acc[u].w * inv;
    ushort4 h4, l4;
    h4.x = f2bf(a0); l4.x = f2bf(a0 - bf2f(h4.x));
    h4.y = f2bf(a1); l4.y = f2bf(a1 - bf2f(h4.y));
    h4.z = f2bf(a2); l4.z = f2bf(a2 - bf2f(h4.z));
    h4.w = f2bf(a3); l4.w = f2bf(a3 - bf2f(h4.w));
    *(ushort4*)(oH + ob + u * 4) = h4;
    *(ushort4*)(oL + ob + u * 4) = l4;
  }
}

// ---------------------------------------------------------------- launch
// Workspace layout — 64 MB total (round-1 kernel proved ws_size >= 72 MB).
//   [ 0, 8M)  h    fp32 residual stream (always live)
//   [ 8,12M)  yH   [12,16M) yL
//   [16,48M)  region C: q(8M)+k(8M)+v(8M) [QKV->attn]
//                     == mlpH(16M)+mlpL(16M) [MLP1->MLP2]
//   [48,64M)  region D, time-multiplexed (stream-ordered hand-offs):
//             qkvo planes (8x2M)  [convert_qkvo .. Wo gemm]
//          -> w1tH(8M)+w1tL(8M)   [convert .. MLP1 gemm]
//          -> w2tH(8M)+w2tL(8M)   [convert .. MLP2 gemm]
//          -> head half-planes htH(8M)+htL(8M), twice  [after last layer]
#define MB (size_t)(1024*1024)

extern "C" void kernel_launch(void* const* d_in, const int* in_sizes, int n_in,
                              void* d_out, int out_size, void* d_ws, size_t ws_size,
                              hipStream_t stream) {
  const int*   x       = (const int*)  d_in[0];
  const float* tok_emb = (const float*)d_in[1];
  const float* pos_emb = (const float*)d_in[2];
  const float* Wq   = (const float*)d_in[3];
  const float* bq   = (const float*)d_in[4];
  const float* Wk   = (const float*)d_in[5];
  const float* bk   = (const float*)d_in[6];
  const float* Wv   = (const float*)d_in[7];
  const float* bv   = (const float*)d_in[8];
  const float* Wo   = (const float*)d_in[9];
  const float* bo   = (const float*)d_in[10];
  const float* ln1w = (const float*)d_in[11];
  const float* ln1b = (const float*)d_in[12];
  const float* ln2w = (const float*)d_in[13];
  const float* ln2b = (const float*)d_in[14];
  const float* W1   = (const float*)d_in[15];
  const float* b1   = (const float*)d_in[16];
  const float* W2   = (const float*)d_in[17];
  const float* b2   = (const float*)d_in[18];
  const float* lnfw = (const float*)d_in[19];
  const float* lnfb = (const float*)d_in[20];
  const float* headW= (const float*)d_in[21];
  float* out = (float*)d_out;

  char* base = (char*)d_ws;
  float* h  = (float*)(base + 0 * MB);
  unsigned short* yH = (unsigned short*)(base + 8 * MB);
  unsigned short* yL = (unsigned short*)(base + 12 * MB);
  // region C
  float* q = (float*)(base + 16 * MB);
  float* k = (float*)(base + 24 * MB);
  float* v = (float*)(base + 32 * MB);
  unsigned short* mlpH = (unsigned short*)(base + 16 * MB);
  unsigned short* mlpL = (unsigned short*)(base + 32 * MB);
  // region D (time-multiplexed weight planes)
  unsigned short* wtH[4], *wtL[4];
  for (int j = 0; j < 4; ++j) {
    wtH[j] = (unsigned short*)(base + 48 * MB + (size_t)(2 * j) * 2 * MB);
    wtL[j] = (unsigned short*)(base + 48 * MB + (size_t)(2 * j + 1) * 2 * MB);
  }
  unsigned short* w1tH = (unsigned short*)(base + 48 * MB);
  unsigned short* w1tL = (unsigned short*)(base + 56 * MB);
  unsigned short* w2tH = (unsigned short*)(base + 48 * MB);
  unsigned short* w2tL = (unsigned short*)(base + 56 * MB);
  unsigned short* htH  = (unsigned short*)(base + 48 * MB);
  unsigned short* htL  = (unsigned short*)(base + 56 * MB);

  embed_kernel<<<(M_ROWS * E / 4) / 256, 256, 0, stream>>>(x, tok_emb, pos_emb, h);

  for (int l = 0; l < L; ++l) {
    // qkv+o weight planes (region D)
    Cv4 cp;
    cp.src[0] = Wq + (size_t)l * E * E; cp.src[1] = Wk + (size_t)l * E * E;
    cp.src[2] = Wv + (size_t)l * E * E; cp.src[3] = Wo + (size_t)l * E * E;
    for (int j = 0; j < 4; ++j) { cp.hi[j] = wtH[j]; cp.lo[j] = wtL[j]; }
    convert_qkvo<<<dim3(E / 64, E / 64, 4), 256, 0, stream>>>(cp);

    ln_kernel<<<M_ROWS, 256, 0, stream>>>(h, ln1w + l * E, ln1b + l * E, yH, yL);

    QkvP qp;
    qp.wH[0] = wtH[0]; qp.wH[1] = wtH[1]; qp.wH[2] = wtH[2];
    qp.wL[0] = wtL[0]; qp.wL[1] = wtL[1]; qp.wL[2] = wtL[2];
    qp.bias[0] = bq + l * E; qp.bias[1] = bk + l * E; qp.bias[2] = bv + l * E;
    qp.out[0] = q; qp.out[1] = k; qp.out[2] = v;
    qkv_gemm<<<dim3(E / 128, M_ROWS / 128, 3), 256, 0, stream>>>(yH, yL, qp);

    attn_kernel<<<dim3(T / TI, H, B), 256, 0, stream>>>(q, k, v, yH, yL);

    gemm_mfma<2><<<dim3(E / 128, M_ROWS / 128), 256, 0, stream>>>(
        yH, yL, wtH[3], wtL[3], bo + l * E, h, nullptr, nullptr, nullptr, E, E);

    // W1 planes overwrite qkvo planes (dead after Wo gemm)
    convert_w<<<dim3(FF / 64, E / 64), 256, 0, stream>>>(
        W1 + (size_t)l * E * FF, w1tH, w1tL, E, FF);

    ln_kernel<<<M_ROWS, 256, 0, stream>>>(h, ln2w + l * E, ln2b + l * E, yH, yL);

    gemm_mfma<1><<<dim3(FF / 128, M_ROWS / 128), 256, 0, stream>>>(
        yH, yL, w1tH, w1tL, b1 + (size_t)l * FF, nullptr, nullptr, mlpH, mlpL, FF, E);

    // W2 planes overwrite W1 planes (dead after MLP1 gemm)
    convert_w<<<dim3(E / 64, FF / 64), 256, 0, stream>>>(
        W2 + (size_t)l * FF * E, w2tH, w2tL, FF, E);

    gemm_mfma<2><<<dim3(E / 128, M_ROWS / 128), 256, 0, stream>>>(
        mlpH, mlpL, w2tH, w2tL, b2 + l * E, h, nullptr, nullptr, nullptr, E, FF);
  }

  ln_kernel<<<M_ROWS, 256, 0, stream>>>(h, lnfw, lnfb, yH, yL);

  // head projection in two column halves (16 MB of planes each, region D)
  for (int hh = 0; hh < 2; ++hh) {
    convert_w<<<dim3((V / 2) / 64, E / 64), 256, 0, stream>>>(
        headW + hh * (V / 2), htH, htL, E, V);
    gemm_mfma<0><<<dim3((V / 2) / 128, M_ROWS / 128), 256, 0, stream>>>(
        yH, yL, htH, htL, nullptr, nullptr, out + hh * (V / 2),
        nullptr, nullptr, V, E);
  }
}